// Round 1
// baseline (114.820 us; speedup 1.0000x reference)
//
#include <hip/hip_runtime.h>

#define VOCAB 50257
#define EMBED 256
#define OUT 5
#define BATCH 512
#define SEQ 512

// Kernel 1: embW[v][o] = dot(emb[v,:], W[o,:])  -- one wave per vocab row.
__global__ __launch_bounds__(256) void k_embw(const float* __restrict__ emb,
                                              const float* __restrict__ W,
                                              float* __restrict__ embW) {
    __shared__ float sW[OUT * EMBED];
    for (int i = threadIdx.x; i < OUT * EMBED; i += 256) sW[i] = W[i];
    __syncthreads();

    const int wave = threadIdx.x >> 6;
    const int lane = threadIdx.x & 63;
    const int v = blockIdx.x * 4 + wave;
    if (v >= VOCAB) return;

    // 64 lanes x float4 = 256 elements: one full embedding row per wave.
    const float4 e = *(const float4*)(emb + (size_t)v * EMBED + lane * 4);

    float p[OUT];
#pragma unroll
    for (int o = 0; o < OUT; ++o) {
        const float4 w = *(const float4*)(sW + o * EMBED + lane * 4);
        p[o] = e.x * w.x + e.y * w.y + e.z * w.z + e.w * w.w;
    }

#pragma unroll
    for (int o = 0; o < OUT; ++o) {
        float val = p[o];
#pragma unroll
        for (int off = 32; off > 0; off >>= 1)
            val += __shfl_down(val, off, 64);
        if (lane == 0) embW[(size_t)v * OUT + o] = val;
    }
}

// Kernel 2: one block per sample. Ragged-sum embW rows, then logits ->
// log-softmax -> per-sample NLL.
__global__ __launch_bounds__(256) void k_pool(const int* __restrict__ x,
                                              const int* __restrict__ lengths,
                                              const int* __restrict__ y,
                                              const float* __restrict__ bias,
                                              const float* __restrict__ embW,
                                              float* __restrict__ losses) {
    const int b = blockIdx.x;
    const int len = lengths[b];
    const int* xb = x + (size_t)b * SEQ;

    float acc[OUT] = {0.f, 0.f, 0.f, 0.f, 0.f};
    for (int s = threadIdx.x; s < len; s += 256) {
        const int tok = xb[s];
        const float* r = embW + (size_t)tok * OUT;
#pragma unroll
        for (int o = 0; o < OUT; ++o) acc[o] += r[o];
    }

#pragma unroll
    for (int o = 0; o < OUT; ++o) {
#pragma unroll
        for (int off = 32; off > 0; off >>= 1)
            acc[o] += __shfl_down(acc[o], off, 64);
    }

    __shared__ float red[4][OUT];
    const int wave = threadIdx.x >> 6;
    const int lane = threadIdx.x & 63;
    if (lane == 0) {
#pragma unroll
        for (int o = 0; o < OUT; ++o) red[wave][o] = acc[o];
    }
    __syncthreads();

    if (threadIdx.x == 0) {
        float logits[OUT];
        const float inv = 1.0f / (float)len;
#pragma unroll
        for (int o = 0; o < OUT; ++o)
            logits[o] = (red[0][o] + red[1][o] + red[2][o] + red[3][o]) * inv + bias[o];

        float m = logits[0];
#pragma unroll
        for (int o = 1; o < OUT; ++o) m = fmaxf(m, logits[o]);
        float sum = 0.f;
#pragma unroll
        for (int o = 0; o < OUT; ++o) sum += __expf(logits[o] - m);
        const float lse = m + __logf(sum);
        losses[b] = lse - logits[y[b]];
    }
}

// Kernel 3: mean over 512 per-sample losses (deterministic, no atomics).
__global__ __launch_bounds__(256) void k_reduce(const float* __restrict__ losses,
                                                float* __restrict__ out) {
    float v = losses[threadIdx.x] + losses[threadIdx.x + 256];
#pragma unroll
    for (int off = 32; off > 0; off >>= 1)
        v += __shfl_down(v, off, 64);
    __shared__ float red[4];
    if ((threadIdx.x & 63) == 0) red[threadIdx.x >> 6] = v;
    __syncthreads();
    if (threadIdx.x == 0)
        out[0] = (red[0] + red[1] + red[2] + red[3]) * (1.0f / (float)BATCH);
}

extern "C" void kernel_launch(void* const* d_in, const int* in_sizes, int n_in,
                              void* d_out, int out_size, void* d_ws, size_t ws_size,
                              hipStream_t stream) {
    const int*   x       = (const int*)d_in[0];
    const int*   lengths = (const int*)d_in[1];
    const int*   y       = (const int*)d_in[2];
    const float* emb     = (const float*)d_in[3];
    const float* W       = (const float*)d_in[4];
    const float* bias    = (const float*)d_in[5];

    float* embW   = (float*)d_ws;                    // VOCAB*OUT floats (~1.0 MB)
    float* losses = embW + (size_t)VOCAB * OUT;      // BATCH floats

    k_embw<<<(VOCAB + 3) / 4, 256, 0, stream>>>(emb, W, embW);
    k_pool<<<BATCH, 256, 0, stream>>>(x, lengths, y, bias, embW, losses);
    k_reduce<<<1, 256, 0, stream>>>(losses, (float*)d_out);
}